// Round 7
// baseline (165.675 us; speedup 1.0000x reference)
//
#include <hip/hip_runtime.h>
#include <hip/hip_bf16.h>
#include <cstdint>
#include <cstddef>

// ---------------------------------------------------------------------------
// LocalAttention: B=4, S=2048, D=1024, WINDOW=10 (|i-j| <= 5)
//   QKV = x @ [Wq;Wk;Wv].T + b   (256^2 counted-vmcnt pipeline, FIXED swizzle)
//   band softmax (f32) -> attn full rows written by kernel (no memset)
//   ctx = attn@V (band, f32 acc -> bf16)
//   out = ctx@Wo.T + bo          (m97 128^2 bf16 MFMA GEMM, f32 out)
// d_out: out [4,2048,1024] f32, attn [4,2048,2048] f32 (concatenated)
// ---------------------------------------------------------------------------

typedef __attribute__((ext_vector_type(8))) short bf16x8;
typedef __attribute__((ext_vector_type(4))) float f32x4;
typedef __attribute__((ext_vector_type(8))) unsigned short ushortx8;

#define GPTR(x) ((const __attribute__((address_space(1))) void*)(x))
#define LPTR(x) ((__attribute__((address_space(3))) void*)(x))

__device__ __forceinline__ unsigned short f2bf(float f) {
    __hip_bfloat16 h = __float2bfloat16(f);
    unsigned short u;
    __builtin_memcpy(&u, &h, 2);
    return u;
}
__device__ __forceinline__ float bf2f(unsigned short u) {
    unsigned int x = ((unsigned int)u) << 16;
    float f;
    __builtin_memcpy(&f, &x, 4);
    return f;
}

// ------------------- fused f32->bf16 convert: x + Wq/Wk/Wv -> Wcat, Wo -----
__global__ void cvt_all(const float* __restrict__ x,
                        const float* __restrict__ Wq, const float* __restrict__ Wk,
                        const float* __restrict__ Wv, const float* __restrict__ Wo,
                        unsigned short* __restrict__ xh,
                        unsigned short* __restrict__ Wcat,
                        unsigned short* __restrict__ Woh) {
    const int idx = blockIdx.x * blockDim.x + threadIdx.x;
    const float* src;
    unsigned short* dst;
    int s_off, d_off;
    if (idx < 2097152) {
        src = x; dst = xh; s_off = idx; d_off = idx;
    } else {
        const int r   = idx - 2097152;
        const int seg = r >> 18;          // 0..3
        const int off = r & 262143;
        src   = (seg == 0) ? Wq : (seg == 1) ? Wk : (seg == 2) ? Wv : Wo;
        dst   = (seg < 3) ? Wcat : Woh;
        s_off = off;
        d_off = (seg < 3) ? (seg << 18) + off : off;
    }
    f32x4 v = reinterpret_cast<const f32x4*>(src)[s_off];
    ushort4 o;
    o.x = f2bf(v[0]); o.y = f2bf(v[1]); o.z = f2bf(v[2]); o.w = f2bf(v[3]);
    reinterpret_cast<ushort4*>(dst)[d_off] = o;
}

// ==================== 256^2 counted-vmcnt GEMM (QKV projection) =============
// A [M,K] bf16 rm, Bw [N,K] bf16 rm, C bf16 [M,N] = A@Bw^T + bias(segmented).
// BM=BN=256, BK=64, 512 thr = 8 waves (2Mx4N), per-wave C = 128x64.
// LDS 128KB: per operand 2 buffers x 2 K-half units [256 rows x 32 K] 16KB.
// Slot bijection (XOR involution, both sides per rule #21):
//   slot = cs ^ (row&3) ^ ((row>>2)&3)
// -> lanes 0-15 (16 consecutive rows, fixed cs) cover all 32 banks exactly
//    2x = free (m136). R5's bug was the missing (row&3) term (4.7M conflicts).
// Schedule per K-tile t (identical to round-5, race-screened):
//   p1: vmcnt(4); s_barrier; stage A-K0(t+1); read B-K0+A-K0(mh0); 16 MFMA
//   p2:                      stage B-K0(t+1); read A-K0(mh1);      16 MFMA
//   p3: vmcnt(4|0); s_barrier; stage A-K1(t+1); read B-K1+A-K1(mh0); 16 MFMA
//   p4:                      stage B-K1(t+1); read A-K1(mh1);      16 MFMA
// vmcnt(4): oldest 4 loads = exactly the 2 units about to be read (T4:
// counted, never 0 in steady state; loads span a full tile of compute).

__device__ __forceinline__ void stage_unit(const char* gtile, size_t rstride,
                                           size_t kbyte, unsigned short* unit,
                                           int w, int lane) {
#pragma unroll
    for (int q = 0; q < 2; ++q) {
        const int s0  = (w << 7) + (q << 6) + lane;      // 16B-slot 0..1023
        const int row = s0 >> 2;                         // 0..255
        const int c   = (s0 ^ (s0 >> 2) ^ (s0 >> 4)) & 3; // inverse swizzle
        __builtin_amdgcn_global_load_lds(
            GPTR(gtile + (size_t)row * rstride + kbyte + (size_t)(c << 4)),
            LPTR((char*)unit + ((w << 11) + (q << 10))),
            16, 0, 0);
    }
}

__device__ __forceinline__ bf16x8 frag(const unsigned short* unit, int row, int cs) {
    const int slot = (row << 2) + ((cs ^ (row & 3) ^ ((row >> 2) & 3)) & 3);
    return *reinterpret_cast<const bf16x8*>((const char*)unit + (slot << 4));
}

__launch_bounds__(512, 1)
__global__ void gemm_qkv_8ph(const unsigned short* __restrict__ A,
                             const unsigned short* __restrict__ Bw,
                             const float* __restrict__ bq,
                             const float* __restrict__ bk,
                             const float* __restrict__ bv,
                             unsigned short* __restrict__ C,
                             int M, int N, int K) {
    __shared__ unsigned short As[2][2][8192];   // [buf][khalf][256x32]
    __shared__ unsigned short Bs[2][2][8192];

    const int tid  = threadIdx.x;
    const int lane = tid & 63;
    const int w    = tid >> 6;       // 0..7
    const int wr   = w >> 2;         // 0..1 -> 128 rows
    const int wc   = w & 3;          // 0..3 -> 64 cols
    const int l15  = lane & 15;
    const int cs   = lane >> 4;      // 0..3 (16B K-slot within K-half)

    // bijective XCD-contiguous swizzle (grid % 8 == 0)
    const int nb    = gridDim.x;
    const int chunk = nb >> 3;
    const int sid   = (blockIdx.x & 7) * chunk + (blockIdx.x >> 3);
    const int ntn   = N >> 8;
    const int tm    = sid / ntn;
    const int tn    = sid % ntn;

    f32x4 acc[8][4];
#pragma unroll
    for (int m = 0; m < 8; ++m)
#pragma unroll
        for (int n = 0; n < 4; ++n) acc[m][n] = (f32x4){0.f, 0.f, 0.f, 0.f};

    const size_t rstride = (size_t)K * 2;
    const char* Ag = (const char*)(A + (size_t)tm * 256 * (size_t)K);
    const char* Bg = (const char*)(Bw + (size_t)tn * 256 * (size_t)K);

    // prologue: stage tile 0 (4 units, 8 loads/thread) into buffer 0
    stage_unit(Ag, rstride, 0,  As[0][0], w, lane);
    stage_unit(Bg, rstride, 0,  Bs[0][0], w, lane);
    stage_unit(Ag, rstride, 64, As[0][1], w, lane);
    stage_unit(Bg, rstride, 64, Bs[0][1], w, lane);

    const int NT = K >> 6;
    int buf = 0;

    for (int t = 0; t < NT; ++t) {
        const bool sv = (t + 1 < NT);
        const unsigned short* A0 = As[buf][0];
        const unsigned short* A1 = As[buf][1];
        const unsigned short* B0 = Bs[buf][0];
        const unsigned short* B1 = Bs[buf][1];
        unsigned short* nA0 = As[buf ^ 1][0];
        unsigned short* nA1 = As[buf ^ 1][1];
        unsigned short* nB0 = Bs[buf ^ 1][0];
        unsigned short* nB1 = Bs[buf ^ 1][1];
        const size_t kb = (size_t)(t + 1) << 7;   // next tile K byte offset

        bf16x8 a[4], b[4];

        // ---------------- phase 1 (kk=0, mh=0) ----------------
        asm volatile("s_waitcnt vmcnt(4)" ::: "memory");   // A-K0,B-K0 landed
        __builtin_amdgcn_s_barrier();                      // ..across all waves
        if (sv) stage_unit(Ag, rstride, kb, nA0, w, lane);
#pragma unroll
        for (int n = 0; n < 4; ++n) b[n] = frag(B0, wc * 64 + n * 16 + l15, cs);
#pragma unroll
        for (int m = 0; m < 4; ++m) a[m] = frag(A0, wr * 128 + m * 16 + l15, cs);
        __builtin_amdgcn_s_setprio(1);
#pragma unroll
        for (int m = 0; m < 4; ++m)
#pragma unroll
            for (int n = 0; n < 4; ++n)
                acc[m][n] = __builtin_amdgcn_mfma_f32_16x16x32_bf16(
                    a[m], b[n], acc[m][n], 0, 0, 0);
        __builtin_amdgcn_s_setprio(0);

        // ---------------- phase 2 (kk=0, mh=1) ----------------
        if (sv) stage_unit(Bg, rstride, kb, nB0, w, lane);
#pragma unroll
        for (int m = 0; m < 4; ++m) a[m] = frag(A0, wr * 128 + 64 + m * 16 + l15, cs);
        __builtin_amdgcn_s_setprio(1);
#pragma unroll
        for (int m = 0; m < 4; ++m)
#pragma unroll
            for (int n = 0; n < 4; ++n)
                acc[4 + m][n] = __builtin_amdgcn_mfma_f32_16x16x32_bf16(
                    a[m], b[n], acc[4 + m][n], 0, 0, 0);
        __builtin_amdgcn_s_setprio(0);

        // ---------------- phase 3 (kk=1, mh=0) ----------------
        if (sv) { asm volatile("s_waitcnt vmcnt(4)" ::: "memory"); }
        else    { asm volatile("s_waitcnt vmcnt(0)" ::: "memory"); }
        __builtin_amdgcn_s_barrier();                      // A-K1,B-K1 landed
        if (sv) stage_unit(Ag, rstride, kb + 64, nA1, w, lane);
#pragma unroll
        for (int n = 0; n < 4; ++n) b[n] = frag(B1, wc * 64 + n * 16 + l15, cs);
#pragma unroll
        for (int m = 0; m < 4; ++m) a[m] = frag(A1, wr * 128 + m * 16 + l15, cs);
        __builtin_amdgcn_s_setprio(1);
#pragma unroll
        for (int m = 0; m < 4; ++m)
#pragma unroll
            for (int n = 0; n < 4; ++n)
                acc[m][n] = __builtin_amdgcn_mfma_f32_16x16x32_bf16(
                    a[m], b[n], acc[m][n], 0, 0, 0);
        __builtin_amdgcn_s_setprio(0);

        // ---------------- phase 4 (kk=1, mh=1) ----------------
        if (sv) stage_unit(Bg, rstride, kb + 64, nB1, w, lane);
#pragma unroll
        for (int m = 0; m < 4; ++m) a[m] = frag(A1, wr * 128 + 64 + m * 16 + l15, cs);
        __builtin_amdgcn_s_setprio(1);
#pragma unroll
        for (int m = 0; m < 4; ++m)
#pragma unroll
            for (int n = 0; n < 4; ++n)
                acc[4 + m][n] = __builtin_amdgcn_mfma_f32_16x16x32_bf16(
                    a[m], b[n], acc[4 + m][n], 0, 0, 0);
        __builtin_amdgcn_s_setprio(0);

        buf ^= 1;
    }

    // epilogue: col = lane&15 (+n*16), row = (lane>>4)*4 + r (+m*16)
    const int col0 = tn * 256 + wc * 64 + l15;
    const int row0 = tm * 256 + wr * 128 + (cs << 2);
#pragma unroll
    for (int n = 0; n < 4; ++n) {
        const int col = col0 + n * 16;
        const int seg = col >> 10;                  // block-uniform per tile
        const float bb = (seg == 0 ? bq : seg == 1 ? bk : bv)[col & 1023];
#pragma unroll
        for (int m = 0; m < 8; ++m) {
            const int row = row0 + m * 16;
#pragma unroll
            for (int r = 0; r < 4; ++r)
                C[(size_t)(row + r) * (size_t)N + col] = f2bf(acc[m][n][r] + bb);
        }
    }
}

// ==================== m97 128^2 GEMM core (output projection) ==============
__device__ __forceinline__ void gemm_core(const unsigned short* __restrict__ A,
                                          const unsigned short* __restrict__ Bw,
                                          int K, int tm, int tn,
                                          unsigned short* As, unsigned short* Bs,
                                          f32x4 (&acc)[4][4]) {
    const int tid  = threadIdx.x;
    const int lane = tid & 63;
    const int w    = tid >> 6;
    const int wr   = w >> 1;
    const int wc   = w & 1;

    const int lrow8 = lane >> 3;
    const int lcolb = (lane & 7) << 4;

    const char* Abase = (const char*)(A + (size_t)tm * 128 * (size_t)K);
    const char* Bbase = (const char*)(Bw + (size_t)tn * 128 * (size_t)K);
    const size_t rstride = (size_t)K * 2;

    const int nk = K >> 6;
    for (int t = 0; t < nk; ++t) {
        const size_t k0b = ((size_t)t << 6) * 2;
#pragma unroll
        for (int ii = 0; ii < 4; ++ii) {
            const int c    = (w << 2) + ii;
            const int row  = (c << 3) + lrow8;
            const int csrc = lcolb ^ ((row & 7) << 4);
            __builtin_amdgcn_global_load_lds(
                GPTR(Abase + (size_t)row * rstride + k0b + (size_t)csrc),
                LPTR((char*)As + (c << 10)), 16, 0, 0);
            __builtin_amdgcn_global_load_lds(
                GPTR(Bbase + (size_t)row * rstride + k0b + (size_t)csrc),
                LPTR((char*)Bs + (c << 10)), 16, 0, 0);
        }
        __syncthreads();

#pragma unroll
        for (int kk = 0; kk < 2; ++kk) {
            bf16x8 af[4], bfr[4];
            const int cb = (kk << 6) + ((lane >> 4) << 4);
#pragma unroll
            for (int m = 0; m < 4; ++m) {
                const int row = (wr << 6) + (m << 4) + (lane & 15);
                af[m] = *reinterpret_cast<const bf16x8*>(
                    (const char*)As + row * 128 + (cb ^ ((row & 7) << 4)));
            }
#pragma unroll
            for (int n = 0; n < 4; ++n) {
                const int row = (wc << 6) + (n << 4) + (lane & 15);
                bfr[n] = *reinterpret_cast<const bf16x8*>(
                    (const char*)Bs + row * 128 + (cb ^ ((row & 7) << 4)));
            }
#pragma unroll
            for (int m = 0; m < 4; ++m)
#pragma unroll
                for (int n = 0; n < 4; ++n)
                    acc[m][n] = __builtin_amdgcn_mfma_f32_16x16x32_bf16(
                        af[m], bfr[n], acc[m][n], 0, 0, 0);
        }
        __syncthreads();
    }
}

// output projection: C f32 [M, 1024]. 1D grid 512 = 64 tm x 8 tn, XCD-chunked.
__launch_bounds__(256, 3)
__global__ void gemm_out(const unsigned short* __restrict__ A,
                         const unsigned short* __restrict__ Bw,
                         const float* __restrict__ bias,
                         float* __restrict__ C, int M, int N, int K) {
    __shared__ unsigned short As[128 * 64];
    __shared__ unsigned short Bs[128 * 64];
    f32x4 acc[4][4];
#pragma unroll
    for (int m = 0; m < 4; ++m)
#pragma unroll
        for (int n = 0; n < 4; ++n) acc[m][n] = (f32x4){0.f, 0.f, 0.f, 0.f};

    const int sid = (blockIdx.x & 7) * (gridDim.x >> 3) + (blockIdx.x >> 3);
    const int tm  = sid >> 3;
    const int tn  = sid & 7;

    gemm_core(A, Bw, K, tm, tn, As, Bs, acc);

    const int lane = threadIdx.x & 63;
    const int w    = threadIdx.x >> 6;
    const int wr   = w >> 1, wc = w & 1;
    const int col0 = (tn << 7) + (wc << 6) + (lane & 15);
    const int row0 = (tm << 7) + (wr << 6) + ((lane >> 4) << 2);
#pragma unroll
    for (int n = 0; n < 4; ++n) {
        const int col = col0 + (n << 4);
        const float bb = bias[col];
#pragma unroll
        for (int m = 0; m < 4; ++m) {
            const int row = row0 + (m << 4);
#pragma unroll
            for (int r = 0; r < 4; ++r)
                C[(size_t)(row + r) * (size_t)N + col] = acc[m][n][r] + bb;
        }
    }
}

// ------------------- band attention, writes FULL attn rows ------------------
// QKV [8192, 3072] bf16 (Q | K | V per row). One wave per (b,i) row.
__launch_bounds__(256, 4)
__global__ void attn_band_kernel(const unsigned short* __restrict__ QKV,
                                 float* __restrict__ attn,
                                 unsigned short* __restrict__ ctx) {
    __shared__ float psm[4][16];
    const int bid  = blockIdx.x;
    const int rb   = (bid & 7) * 256 + (bid >> 3);   // XCD-contiguous swizzle
    const int w    = threadIdx.x >> 6;
    const int lane = threadIdx.x & 63;
    const int g    = (rb << 2) + w;                  // row 0..8191
    const int b    = g >> 11;
    const int i    = g & 2047;

    const unsigned short* qrow = QKV + (size_t)g * 3072;
    float qf[16];
    {
        ushortx8 qa = *reinterpret_cast<const ushortx8*>(qrow + (lane << 4));
        ushortx8 qb = *reinterpret_cast<const ushortx8*>(qrow + (lane << 4) + 8);
#pragma unroll
        for (int t = 0; t < 8; ++t) { qf[t] = bf2f(qa[t]); qf[8 + t] = bf2f(qb[t]); }
    }

    float s[11];
#pragma unroll
    for (int jj = 0; jj < 11; ++jj) {
        const int j = i - 5 + jj;
        const bool valid = ((unsigned)j < 2048u);
        const int jc = min(max(j, 0), 2047);
        const unsigned short* krow = QKV + ((size_t)(b << 11) + jc) * 3072 + 1024;
        ushortx8 ka = *reinterpret_cast<const ushortx8*>(krow + (lane << 4));
        ushortx8 kb = *reinterpret_cast<const ushortx8*>(krow + (lane << 4) + 8);
        float d = 0.f;
#pragma unroll
        for (int t = 0; t < 8; ++t)
            d += qf[t] * bf2f(ka[t]) + qf[8 + t] * bf2f(kb[t]);
#pragma unroll
        for (int off = 32; off >= 1; off >>= 1) d += __shfl_xor(d, off, 64);
        s[jj] = valid ? d * 0.03125f : -1e30f;       // 1/sqrt(1024)
    }

    float mx = s[0];
#pragma unroll
    for (int jj = 1; jj < 11; ++jj) mx = fmaxf(mx, s[jj]);
    float p[11], sum = 0.f;
#pragma unroll
    for (int jj = 0; jj < 11; ++jj) { p[jj] = expf(s[jj] - mx); sum += p[jj]; }
    const float inv = 1.0f / sum;

    if (lane == 0) {
#pragma unroll
        for (int jj = 0; jj < 11; ++jj) psm[w][jj] = p[jj] * inv;
    }
    __syncthreads();

    const int lo = i - 5;
    float* arow = attn + (size_t)g * 2048;
#pragma unroll
    for (int e = 0; e < 8; ++e) {
        const int c0 = (e << 8) + (lane << 2);
        f32x4 v = (f32x4){0.f, 0.f, 0.f, 0.f};
        if (c0 + 3 >= lo && c0 <= lo + 10) {
#pragma unroll
            for (int t = 0; t < 4; ++t) {
                const int d = c0 + t - lo;
                if ((unsigned)d < 11u) v[t] = psm[w][d];
            }
        }
        *reinterpret_cast<f32x4*>(arow + c0) = v;
    }

    float cacc[16];
#pragma unroll
    for (int t = 0; t < 16; ++t) cacc[t] = 0.f;
#pragma unroll
    for (int jj = 0; jj < 11; ++jj) {
        const int j  = i - 5 + jj;
        const int jc = min(max(j, 0), 2047);
        const float pj = p[jj] * inv;                // 0 for invalid j
        const unsigned short* vrow = QKV + ((size_t)(b << 11) + jc) * 3072 + 2048;
        ushortx8 va = *reinterpret_cast<const ushortx8*>(vrow + (lane << 4));
        ushortx8 vb = *reinterpret_cast<const ushortx8*>(vrow + (lane << 4) + 8);
#pragma unroll
        for (int t = 0; t < 8; ++t) {
            cacc[t]     += pj * bf2f(va[t]);
            cacc[8 + t] += pj * bf2f(vb[t]);
        }
    }
    unsigned short* cp = ctx + (size_t)g * 1024 + (lane << 4);
    ushortx8 oa, ob;
#pragma unroll
    for (int t = 0; t < 8; ++t) { oa[t] = f2bf(cacc[t]); ob[t] = f2bf(cacc[8 + t]); }
    *reinterpret_cast<ushortx8*>(cp)     = oa;
    *reinterpret_cast<ushortx8*>(cp + 8) = ob;
}

// ------------------------------ launch --------------------------------------
extern "C" void kernel_launch(void* const* d_in, const int* in_sizes, int n_in,
                              void* d_out, int out_size, void* d_ws, size_t ws_size,
                              hipStream_t stream) {
    const float* x  = (const float*)d_in[0];
    const float* Wq = (const float*)d_in[1];
    const float* bq = (const float*)d_in[2];
    const float* Wk = (const float*)d_in[3];
    const float* bk = (const float*)d_in[4];
    const float* Wv = (const float*)d_in[5];
    const float* bv = (const float*)d_in[6];
    const float* Wo = (const float*)d_in[7];
    const float* bo = (const float*)d_in[8];

    const size_t MS = 8192, DD = 1024;

    float* out  = (float*)d_out;              // [8192,1024] f32
    float* attn = out + MS * DD;              // [4,2048,2048] f32

    char* ws = (char*)d_ws;
    unsigned short* xh   = (unsigned short*)ws; ws += MS * DD * 2;
    unsigned short* Wcat = (unsigned short*)ws; ws += 3 * DD * DD * 2;
    unsigned short* Woh  = (unsigned short*)ws; ws += DD * DD * 2;
    unsigned short* QKV  = (unsigned short*)ws; ws += MS * 3 * DD * 2;
    unsigned short* ctx  = (unsigned short*)ws; ws += MS * DD * 2;

    // 1) converts
    cvt_all<<<dim3(12288), dim3(256), 0, stream>>>(x, Wq, Wk, Wv, Wo, xh, Wcat, Woh);

    // 2) fused QKV projection, counted-vmcnt pipeline (fixed swizzle)
    gemm_qkv_8ph<<<dim3(384), dim3(512), 0, stream>>>(xh, Wcat, bq, bk, bv,
                                                      QKV, 8192, 3072, 1024);

    // 3) band attention: full attn rows -> d_out, ctx bf16 -> ws
    attn_band_kernel<<<dim3(2048), dim3(256), 0, stream>>>(QKV, attn, ctx);

    // 4) output projection: ctx @ Wo^T + bo -> f32 out
    gemm_out<<<dim3(512), dim3(256), 0, stream>>>(ctx, Woh, bo, out, 8192, 1024, 1024);
}

// Round 8
// 132.784 us; speedup vs baseline: 1.2477x; 1.2477x over previous
//
#include <hip/hip_runtime.h>
#include <hip/hip_bf16.h>
#include <cstdint>
#include <cstddef>

// ---------------------------------------------------------------------------
// LocalAttention: B=4, S=2048, D=1024, WINDOW=10 (|i-j| <= 5)
// Wo-fold: out = attn @ Vp + bo, where Vp = x @ (Wo@Wv)^T + Wo@bv.
//   cvt: x,Wq,Wk -> bf16 (Wcat seg0/1), Wo -> Woh
//   transpose_cvt: Wv f32 -> Wvt bf16 (transposed)
//   bvo = Wo @ bv (f32)
//   Wp = Woh @ Wvt^T   (m97 GEMM, bf16 -> Wcat seg2)
//   QKV = x @ [Wq;Wk;Wp].T + [bq;bk;bvo]  (m97 128^2 GEMM -> Q|K|Vp bf16)
//   band attn: attn rows -> d_out; out = sum p_j Vp[j] + bo -> d_out (f32)
// d_out: out [4,2048,1024] f32, attn [4,2048,2048] f32 (concatenated)
// ---------------------------------------------------------------------------

typedef __attribute__((ext_vector_type(8))) short bf16x8;
typedef __attribute__((ext_vector_type(4))) float f32x4;
typedef __attribute__((ext_vector_type(8))) unsigned short ushortx8;

#define GPTR(x) ((const __attribute__((address_space(1))) void*)(x))
#define LPTR(x) ((__attribute__((address_space(3))) void*)(x))

__device__ __forceinline__ unsigned short f2bf(float f) {
    __hip_bfloat16 h = __float2bfloat16(f);
    unsigned short u;
    __builtin_memcpy(&u, &h, 2);
    return u;
}
__device__ __forceinline__ float bf2f(unsigned short u) {
    unsigned int x = ((unsigned int)u) << 16;
    float f;
    __builtin_memcpy(&f, &x, 4);
    return f;
}

// ------------------- fused f32->bf16 convert: x, Wq, Wk -> Wcat; Wo -> Woh --
__global__ void cvt_all(const float* __restrict__ x,
                        const float* __restrict__ Wq, const float* __restrict__ Wk,
                        const float* __restrict__ Wo,
                        unsigned short* __restrict__ xh,
                        unsigned short* __restrict__ Wcat,
                        unsigned short* __restrict__ Woh) {
    const int idx = blockIdx.x * blockDim.x + threadIdx.x;   // 0..2883583
    const float* src;
    unsigned short* dst;
    int s_off, d_off;
    if (idx < 2097152) {
        src = x; dst = xh; s_off = idx; d_off = idx;
    } else {
        const int r   = idx - 2097152;
        const int seg = r >> 18;          // 0:Wq 1:Wk 2:Wo
        const int off = r & 262143;
        src   = (seg == 0) ? Wq : (seg == 1) ? Wk : Wo;
        dst   = (seg < 2) ? Wcat : Woh;
        s_off = off;
        d_off = (seg < 2) ? (seg << 18) + off : off;
    }
    f32x4 v = reinterpret_cast<const f32x4*>(src)[s_off];
    ushort4 o;
    o.x = f2bf(v[0]); o.y = f2bf(v[1]); o.z = f2bf(v[2]); o.w = f2bf(v[3]);
    reinterpret_cast<ushort4*>(dst)[d_off] = o;
}

// ------------------- Wv f32 [1024][1024] -> Wvt bf16 transposed -------------
// Wvt[n][k] = Wv[k][n]. 64x64 LDS tile, +1 pad, grid (16,16), 256 threads.
__global__ void transpose_cvt(const float* __restrict__ in,
                              unsigned short* __restrict__ out) {
    __shared__ float tl[64][65];
    const int t  = threadIdx.x;
    const int c  = t & 63;
    const int r4 = t >> 6;                 // 0..3
    const int bx = blockIdx.x;             // input col tile
    const int by = blockIdx.y;             // input row tile
#pragma unroll
    for (int i = 0; i < 16; ++i) {
        const int r = r4 * 16 + i;
        tl[r][c] = in[(size_t)(by * 64 + r) * 1024 + bx * 64 + c];
    }
    __syncthreads();
#pragma unroll
    for (int i = 0; i < 16; ++i) {
        const int r = r4 * 16 + i;         // output row within tile
        out[(size_t)(bx * 64 + r) * 1024 + by * 64 + c] = f2bf(tl[c][r]);
    }
}

// ------------------- bvo = Wo @ bv (f32), one wave per row ------------------
__global__ void bvo_kernel(const float* __restrict__ Wo,
                           const float* __restrict__ bv,
                           float* __restrict__ bvo) {
    const int row  = blockIdx.x * 4 + (threadIdx.x >> 6);
    const int lane = threadIdx.x & 63;
    float s = 0.f;
#pragma unroll
    for (int k = lane; k < 1024; k += 64)
        s += Wo[(size_t)row * 1024 + k] * bv[k];
#pragma unroll
    for (int off = 32; off >= 1; off >>= 1) s += __shfl_xor(s, off, 64);
    if (lane == 0) bvo[row] = s;
}

// ------------------- GEMM core: 128x128 tile, BK=64, 4 waves (m97) ---------
// A [M,K] bf16 rm, Bw [N,K] bf16 rm; acc = A_tile @ Bw_tile^T.
// global_load_lds w16, linear LDS dest, T2 swizzle via inverse-swizzled
// global source + swizzled ds_read (rule #21). 0 bank conflicts (measured).
__device__ __forceinline__ void gemm_core(const unsigned short* __restrict__ A,
                                          const unsigned short* __restrict__ Bw,
                                          int K, int tm, int tn,
                                          unsigned short* As, unsigned short* Bs,
                                          f32x4 (&acc)[4][4]) {
    const int tid  = threadIdx.x;
    const int lane = tid & 63;
    const int w    = tid >> 6;
    const int wr   = w >> 1;
    const int wc   = w & 1;

    const int lrow8 = lane >> 3;
    const int lcolb = (lane & 7) << 4;

    const char* Abase = (const char*)(A + (size_t)tm * 128 * (size_t)K);
    const char* Bbase = (const char*)(Bw + (size_t)tn * 128 * (size_t)K);
    const size_t rstride = (size_t)K * 2;

    const int nk = K >> 6;
    for (int t = 0; t < nk; ++t) {
        const size_t k0b = ((size_t)t << 6) * 2;
#pragma unroll
        for (int ii = 0; ii < 4; ++ii) {
            const int c    = (w << 2) + ii;
            const int row  = (c << 3) + lrow8;
            const int csrc = lcolb ^ ((row & 7) << 4);
            __builtin_amdgcn_global_load_lds(
                GPTR(Abase + (size_t)row * rstride + k0b + (size_t)csrc),
                LPTR((char*)As + (c << 10)), 16, 0, 0);
            __builtin_amdgcn_global_load_lds(
                GPTR(Bbase + (size_t)row * rstride + k0b + (size_t)csrc),
                LPTR((char*)Bs + (c << 10)), 16, 0, 0);
        }
        __syncthreads();

#pragma unroll
        for (int kk = 0; kk < 2; ++kk) {
            bf16x8 af[4], bfr[4];
            const int cb = (kk << 6) + ((lane >> 4) << 4);
#pragma unroll
            for (int m = 0; m < 4; ++m) {
                const int row = (wr << 6) + (m << 4) + (lane & 15);
                af[m] = *reinterpret_cast<const bf16x8*>(
                    (const char*)As + row * 128 + (cb ^ ((row & 7) << 4)));
            }
#pragma unroll
            for (int n = 0; n < 4; ++n) {
                const int row = (wc << 6) + (n << 4) + (lane & 15);
                bfr[n] = *reinterpret_cast<const bf16x8*>(
                    (const char*)Bs + row * 128 + (cb ^ ((row & 7) << 4)));
            }
#pragma unroll
            for (int m = 0; m < 4; ++m)
#pragma unroll
                for (int n = 0; n < 4; ++n)
                    acc[m][n] = __builtin_amdgcn_mfma_f32_16x16x32_bf16(
                        af[m], bfr[n], acc[m][n], 0, 0, 0);
        }
        __syncthreads();
    }
}

// ------------------- Wp = Woh @ Wvt^T -> bf16 (no bias) ---------------------
// M=N=K=1024, grid 64 = 8x8 tiles, XCD-chunked.
__launch_bounds__(256, 3)
__global__ void gemm_wp(const unsigned short* __restrict__ A,
                        const unsigned short* __restrict__ Bw,
                        unsigned short* __restrict__ C) {
    __shared__ unsigned short As[128 * 64];
    __shared__ unsigned short Bs[128 * 64];
    f32x4 acc[4][4];
#pragma unroll
    for (int m = 0; m < 4; ++m)
#pragma unroll
        for (int n = 0; n < 4; ++n) acc[m][n] = (f32x4){0.f, 0.f, 0.f, 0.f};

    const int sid = (blockIdx.x & 7) * 8 + (blockIdx.x >> 3);
    const int tm  = sid >> 3;
    const int tn  = sid & 7;

    gemm_core(A, Bw, 1024, tm, tn, As, Bs, acc);

    const int lane = threadIdx.x & 63;
    const int w    = threadIdx.x >> 6;
    const int wr   = w >> 1, wc = w & 1;
    const int col0 = (tn << 7) + (wc << 6) + (lane & 15);
    const int row0 = (tm << 7) + (wr << 6) + ((lane >> 4) << 2);
#pragma unroll
    for (int n = 0; n < 4; ++n) {
        const int col = col0 + (n << 4);
#pragma unroll
        for (int m = 0; m < 4; ++m) {
            const int row = row0 + (m << 4);
#pragma unroll
            for (int r = 0; r < 4; ++r)
                C[(size_t)(row + r) * 1024 + col] = f2bf(acc[m][n][r]);
        }
    }
}

// fused QKV projection: C bf16 [M, 3072] = Q|K|Vp, bias per column segment.
// 1D grid 1536 = 64 tm x 24 tn, XCD-chunked.
__launch_bounds__(256, 3)
__global__ void gemm_qkv(const unsigned short* __restrict__ A,
                         const unsigned short* __restrict__ Bw,
                         const float* __restrict__ bq, const float* __restrict__ bk,
                         const float* __restrict__ bvo,
                         unsigned short* __restrict__ C, int M, int N, int K) {
    __shared__ unsigned short As[128 * 64];
    __shared__ unsigned short Bs[128 * 64];
    f32x4 acc[4][4];
#pragma unroll
    for (int m = 0; m < 4; ++m)
#pragma unroll
        for (int n = 0; n < 4; ++n) acc[m][n] = (f32x4){0.f, 0.f, 0.f, 0.f};

    const int ntn = N >> 7;                                  // 24
    const int sid = (blockIdx.x & 7) * (gridDim.x >> 3) + (blockIdx.x >> 3);
    const int tm  = sid / ntn;
    const int tn  = sid % ntn;

    gemm_core(A, Bw, K, tm, tn, As, Bs, acc);

    const int lane = threadIdx.x & 63;
    const int w    = threadIdx.x >> 6;
    const int wr   = w >> 1, wc = w & 1;
    const int seg  = tn >> 3;   // 0:Q 1:K 2:Vp
    const float* bp = (seg == 0) ? bq : (seg == 1) ? bk : bvo;

    const int col0 = (tn << 7) + (wc << 6) + (lane & 15);
    const int row0 = (tm << 7) + (wr << 6) + ((lane >> 4) << 2);
#pragma unroll
    for (int n = 0; n < 4; ++n) {
        const int col = col0 + (n << 4);
        const float bb = bp[col & 1023];
#pragma unroll
        for (int m = 0; m < 4; ++m) {
            const int row = row0 + (m << 4);
#pragma unroll
            for (int r = 0; r < 4; ++r)
                C[(size_t)(row + r) * (size_t)N + col] = f2bf(acc[m][n][r] + bb);
        }
    }
}

// ------------------- band attention: attn rows + final out ------------------
// QKV [8192, 3072] bf16 (Q | K | Vp per row). One wave per (b,i) row.
// out[g] = sum_j p_j * Vp[j] + bo   (f32, written directly to d_out)
__launch_bounds__(256, 4)
__global__ void attn_band_kernel(const unsigned short* __restrict__ QKV,
                                 const float* __restrict__ bo,
                                 float* __restrict__ attn,
                                 float* __restrict__ outp) {
    __shared__ float psm[4][16];
    const int bid  = blockIdx.x;
    const int rb   = (bid & 7) * 256 + (bid >> 3);   // XCD-contiguous swizzle
    const int w    = threadIdx.x >> 6;
    const int lane = threadIdx.x & 63;
    const int g    = (rb << 2) + w;                  // row 0..8191
    const int b    = g >> 11;
    const int i    = g & 2047;

    const unsigned short* qrow = QKV + (size_t)g * 3072;
    float qf[16];
    {
        ushortx8 qa = *reinterpret_cast<const ushortx8*>(qrow + (lane << 4));
        ushortx8 qb = *reinterpret_cast<const ushortx8*>(qrow + (lane << 4) + 8);
#pragma unroll
        for (int t = 0; t < 8; ++t) { qf[t] = bf2f(qa[t]); qf[8 + t] = bf2f(qb[t]); }
    }

    float s[11];
#pragma unroll
    for (int jj = 0; jj < 11; ++jj) {
        const int j = i - 5 + jj;
        const bool valid = ((unsigned)j < 2048u);
        const int jc = min(max(j, 0), 2047);
        const unsigned short* krow = QKV + ((size_t)(b << 11) + jc) * 3072 + 1024;
        ushortx8 ka = *reinterpret_cast<const ushortx8*>(krow + (lane << 4));
        ushortx8 kb = *reinterpret_cast<const ushortx8*>(krow + (lane << 4) + 8);
        float d = 0.f;
#pragma unroll
        for (int t = 0; t < 8; ++t)
            d += qf[t] * bf2f(ka[t]) + qf[8 + t] * bf2f(kb[t]);
#pragma unroll
        for (int off = 32; off >= 1; off >>= 1) d += __shfl_xor(d, off, 64);
        s[jj] = valid ? d * 0.03125f : -1e30f;       // 1/sqrt(1024)
    }

    float mx = s[0];
#pragma unroll
    for (int jj = 1; jj < 11; ++jj) mx = fmaxf(mx, s[jj]);
    float p[11], sum = 0.f;
#pragma unroll
    for (int jj = 0; jj < 11; ++jj) { p[jj] = expf(s[jj] - mx); sum += p[jj]; }
    const float inv = 1.0f / sum;

    if (lane == 0) {
#pragma unroll
        for (int jj = 0; jj < 11; ++jj) psm[w][jj] = p[jj] * inv;
    }
    __syncthreads();

    const int lo = i - 5;
    float* arow = attn + (size_t)g * 2048;
#pragma unroll
    for (int e = 0; e < 8; ++e) {
        const int c0 = (e << 8) + (lane << 2);
        f32x4 v = (f32x4){0.f, 0.f, 0.f, 0.f};
        if (c0 + 3 >= lo && c0 <= lo + 10) {
#pragma unroll
            for (int t = 0; t < 4; ++t) {
                const int d = c0 + t - lo;
                if ((unsigned)d < 11u) v[t] = psm[w][d];
            }
        }
        *reinterpret_cast<f32x4*>(arow + c0) = v;
    }

    float cacc[16];
#pragma unroll
    for (int t = 0; t < 16; ++t) cacc[t] = 0.f;
#pragma unroll
    for (int jj = 0; jj < 11; ++jj) {
        const int j  = i - 5 + jj;
        const int jc = min(max(j, 0), 2047);
        const float pj = p[jj] * inv;                // 0 for invalid j
        const unsigned short* vrow = QKV + ((size_t)(b << 11) + jc) * 3072 + 2048;
        ushortx8 va = *reinterpret_cast<const ushortx8*>(vrow + (lane << 4));
        ushortx8 vb = *reinterpret_cast<const ushortx8*>(vrow + (lane << 4) + 8);
#pragma unroll
        for (int t = 0; t < 8; ++t) {
            cacc[t]     += pj * bf2f(va[t]);
            cacc[8 + t] += pj * bf2f(vb[t]);
        }
    }
    // out = cacc + bo  (f32, 64B per lane)
    const int c0 = lane << 4;
    float* op = outp + (size_t)g * 1024 + c0;
#pragma unroll
    for (int q = 0; q < 4; ++q) {
        f32x4 bb = *reinterpret_cast<const f32x4*>(bo + c0 + (q << 2));
        f32x4 o;
#pragma unroll
        for (int t = 0; t < 4; ++t) o[t] = cacc[(q << 2) + t] + bb[t];
        *reinterpret_cast<f32x4*>(op + (q << 2)) = o;
    }
}

// ------------------------------ launch --------------------------------------
extern "C" void kernel_launch(void* const* d_in, const int* in_sizes, int n_in,
                              void* d_out, int out_size, void* d_ws, size_t ws_size,
                              hipStream_t stream) {
    const float* x  = (const float*)d_in[0];
    const float* Wq = (const float*)d_in[1];
    const float* bq = (const float*)d_in[2];
    const float* Wk = (const float*)d_in[3];
    const float* bk = (const float*)d_in[4];
    const float* Wv = (const float*)d_in[5];
    const float* bv = (const float*)d_in[6];
    const float* Wo = (const float*)d_in[7];
    const float* bo = (const float*)d_in[8];

    const size_t MS = 8192, DD = 1024;

    float* out  = (float*)d_out;              // [8192,1024] f32
    float* attn = out + MS * DD;              // [4,2048,2048] f32

    char* ws = (char*)d_ws;
    unsigned short* xh   = (unsigned short*)ws; ws += MS * DD * 2;        // 16.8 MB
    unsigned short* Wcat = (unsigned short*)ws; ws += 3 * DD * DD * 2;    // 6.3 MB (Q|K|Wp)
    unsigned short* Woh  = (unsigned short*)ws; ws += DD * DD * 2;        // 2.1 MB
    unsigned short* Wvt  = (unsigned short*)ws; ws += DD * DD * 2;        // 2.1 MB
    float*          bvo  = (float*)ws;          ws += DD * 4;             // 4 KB
    unsigned short* QKV  = (unsigned short*)ws; ws += MS * 3 * DD * 2;    // 50.3 MB

    // 1) independent prep kernels
    bvo_kernel<<<dim3(256), dim3(256), 0, stream>>>(Wo, bv, bvo);
    transpose_cvt<<<dim3(16, 16), dim3(256), 0, stream>>>(Wv, Wvt);
    cvt_all<<<dim3(11264), dim3(256), 0, stream>>>(x, Wq, Wk, Wo, xh, Wcat, Woh);

    // 2) Wp = Wo @ Wv (bf16) -> Wcat seg2
    gemm_wp<<<dim3(64), dim3(256), 0, stream>>>(Woh, Wvt, Wcat + 2 * DD * DD);

    // 3) fused QKV projection: Q|K|Vp = x @ [Wq;Wk;Wp]^T + [bq;bk;bvo]
    gemm_qkv<<<dim3(1536), dim3(256), 0, stream>>>(xh, Wcat, bq, bk, bvo,
                                                   QKV, 8192, 3072, 1024);

    // 4) band attention: attn rows + final out (with bo) -> d_out
    attn_band_kernel<<<dim3(2048), dim3(256), 0, stream>>>(QKV, bo, attn, out);
}